// Round 1
// baseline (11238.075 us; speedup 1.0000x reference)
//
#include <hip/hip_runtime.h>
#include <cstdint>
#include <cstddef>

typedef __attribute__((ext_vector_type(8))) short short8;
typedef __attribute__((ext_vector_type(4))) float f32x4;
typedef __attribute__((ext_vector_type(4))) unsigned int u32x4;

union U4S8 { u32x4 u; short8 s; unsigned w[4]; };

#define TSTEPS 199
#define NWG    256u
#define WF_PLANE 786432u   // 128*96*64 u32x4 per hi/lo plane

// ---- workspace layout (bytes) ----
#define WS_BAR   0u         // 2 x u32 barrier
#define WS_ZB    64u        // 2 x 128 x 256   z bit rows (double buffered)
#define WS_XSB   65600u     // 199 x 128 x 128 encoder spike bit rows
#define WS_PART  3326016u   // 2 x 2 x 128 x 64 x 36 f32 readout partials
#define WS_WF    8044608u   // 2 x 128 x 96 x 64 x 16 pre-swizzled bf16 hi/lo B fragments
#define WS_NEED  33210432u

// ---------------- encoder: constant-current LIF -> spike bit rows ----------------
extern "C" __global__ __launch_bounds__(1024) void k_encode(
    const float* __restrict__ x, unsigned char* __restrict__ xsb)
{
  const int b = blockIdx.x;
  const int tid = threadIdx.x;                    // == concatenated input feature index
  const float xv = (tid < 512) ? x[b * 512 + tid] : x[b * 512 + tid - 512];
  const float I = (tid < 512) ? fmaxf(__fmul_rn(50.0f, xv), 0.0f)
                              : fmaxf(__fmul_rn(-50.0f, xv), 0.0f);
  float v = 0.0f;
  unsigned long long* dst =
      (unsigned long long*)(xsb + (size_t)b * 128u + (size_t)(tid >> 6) * 8u);
  for (int t = 0; t < TSTEPS; ++t) {
    v = __fadd_rn(v, __fmul_rn(0.1f, __fsub_rn(I, v)));
    const bool z = v > 1.0f;
    if (z) v = 0.0f;
    const unsigned long long m = __ballot(z ? 1 : 0);
    if ((tid & 63) == 0) dst[(size_t)t * 2048u] = m;   // t stride = 128*128 B
  }
}

// ---------------- weight prep: hi/lo bf16 split into MFMA-fragment order ----------------
__device__ __forceinline__ unsigned bf16rne(float f) {
  const unsigned u = __float_as_uint(f);
  return ((u + 0x7FFFu + ((u >> 16) & 1u)) >> 16) & 0xFFFFu;
}

extern "C" __global__ __launch_bounds__(256) void k_prep(
    const float* __restrict__ w_rec, const float* __restrict__ w_in,
    u32x4* __restrict__ wf)
{
  const unsigned idx  = blockIdx.x * 256u + threadIdx.x;   // 786432 total
  const unsigned lane = idx & 63u;
  const unsigned kt   = (idx >> 6) % 96u;
  const unsigned ns   = idx / 6144u;
  const unsigned j    = ns * 16u + (lane & 15u);
  const unsigned k0   = kt * 32u + (lane >> 4) * 8u;
  unsigned hi[4], lo[4];
#pragma unroll
  for (int u2 = 0; u2 < 4; ++u2) {
    unsigned hb[2], lb[2];
#pragma unroll
    for (int c = 0; c < 2; ++c) {
      const unsigned k = k0 + 2u * (unsigned)u2 + (unsigned)c;
      float w;
      if (k < 2048u) w = (k == j) ? 0.0f : w_rec[(size_t)j * 2048u + k];
      else           w = w_in[(size_t)j * 1024u + (k - 2048u)];
      const unsigned h = bf16rne(w);
      const float hvf = __uint_as_float(h << 16);
      const unsigned l = bf16rne(__fsub_rn(w, hvf));
      hb[c] = h; lb[c] = l;
    }
    hi[u2] = hb[0] | (hb[1] << 16);
    lo[u2] = lb[0] | (lb[1] << 16);
  }
  u32x4 vh, vl;
  vh[0] = hi[0]; vh[1] = hi[1]; vh[2] = hi[2]; vh[3] = hi[3];
  vl[0] = lo[0]; vl[1] = lo[1]; vl[2] = lo[2]; vl[3] = lo[3];
  wf[idx] = vh;
  wf[idx + WF_PLANE] = vl;
}

// ---------------- device-scope grid barrier ----------------
__device__ __forceinline__ void grid_barrier(unsigned* bar)
{
  __syncthreads();
  if (threadIdx.x == 0) {
    __threadfence();   // release: publish z bits / partials device-wide
    const unsigned g = __hip_atomic_load(bar + 1, __ATOMIC_RELAXED, __HIP_MEMORY_SCOPE_AGENT);
    const unsigned prev = __hip_atomic_fetch_add(bar, 1u, __ATOMIC_ACQ_REL, __HIP_MEMORY_SCOPE_AGENT);
    if (prev == NWG - 1u) {
      __hip_atomic_store(bar, 0u, __ATOMIC_RELAXED, __HIP_MEMORY_SCOPE_AGENT);
      __hip_atomic_store(bar + 1, g + 1u, __ATOMIC_RELEASE, __HIP_MEMORY_SCOPE_AGENT);
    } else {
      while (__hip_atomic_load(bar + 1, __ATOMIC_RELAXED, __HIP_MEMORY_SCOPE_AGENT) == g) {
        __builtin_amdgcn_s_sleep(1);
      }
    }
    __threadfence();   // acquire: invalidate stale lines before reading others' data
  }
  __syncthreads();
}

// ---------------- main persistent ALIF kernel ----------------
// grid 256: wg = mh(2 batch halves) x ns(128 slices of 16 neurons), 256 threads (4 waves, K-split)
extern "C" __global__ __launch_bounds__(256) void k_main(
    const u32x4* __restrict__ wf,
    const unsigned char* __restrict__ xsb,
    unsigned char* __restrict__ zb,
    float* __restrict__ part,
    const float* __restrict__ w_out,
    const float* __restrict__ w_li,
    unsigned* __restrict__ bar,
    float* __restrict__ out)
{
  __shared__ unsigned abytes[64][100];      // 64 batch rows x 384B of A bits (dword padded)
  __shared__ float red[4][64][17];          // per-wave partial acc
  __shared__ unsigned char zn[64][4];
  __shared__ unsigned short zrow[64];
  __shared__ float red2[33][4];
  __shared__ float sm[33];

  const unsigned tid  = threadIdx.x;
  const unsigned wg   = blockIdx.x;
  const unsigned mh   = wg >> 7;
  const unsigned ns   = wg & 127u;
  const unsigned wv   = tid >> 6;
  const unsigned lane = tid & 63u;
  const unsigned ln15 = lane & 15u;
  const unsigned shg  = (lane >> 4) * 8u;
  const unsigned g4   = lane >> 4;
  const unsigned blq  = tid & 63u;          // owned batch row
  const unsigned q    = tid >> 6;           // owned neuron quad

  const u32x4* WH = wf + (size_t)ns * 6144u;
  const u32x4* WL = wf + WF_PLANE + (size_t)ns * 6144u;

  float v[4]  = {0.f, 0.f, 0.f, 0.f};
  float a[4]  = {0.f, 0.f, 0.f, 0.f};
  float zf[4] = {0.f, 0.f, 0.f, 0.f};
  float vo = 0.f, voMax = 0.f, liv = 0.f, lii = 0.f, liMax = 0.f;

  for (int t = 0; t < TSTEPS; ++t) {
    // ---- accumulate readout of step t-1 (b-owner wgs only, overlapped) ----
    if (wg < 128u && t > 0) {
      const unsigned pr = (unsigned)(t - 1) & 1u;
      if (tid < 132u) {
        const unsigned o = tid >> 2, c = tid & 3u;
        const float* pp = part +
            ((((size_t)pr * 2u + (wg >> 6)) * 128u + c * 32u) * 64u + (wg & 63u)) * 36u + o;
        float s = 0.f;
#pragma unroll 8
        for (unsigned n2 = 0; n2 < 32u; ++n2) s += pp[(size_t)n2 * (64u * 36u)];
        red2[o][c] = s;
      }
      __syncthreads();
      if (tid < 132u && (tid & 3u) == 0u) {
        const unsigned o = tid >> 2;
        const float s = (red2[o][0] + red2[o][1]) + (red2[o][2] + red2[o][3]);
        if (o < 32u) {
          vo = __fadd_rn(__fmul_rn(0.8f, vo), s);
          voMax = fmaxf(voMax, vo);
        } else {
          const float ij = __fadd_rn(lii, s);
          liv = __fadd_rn(liv, __fmul_rn(0.1f, __fsub_rn(ij, liv)));
          lii = __fsub_rn(ij, __fmul_rn(0.2f, ij));
          liMax = fmaxf(liMax, liv);
        }
      }
    }
    // ---- stage A bit rows (z_t-1 || xs_t) into LDS ----
    {
      const unsigned char* zr = zb + (size_t)(t & 1) * 32768u + (size_t)mh * 64u * 256u;
      for (unsigned i = tid; i < 4096u; i += 256u) {
        const unsigned row = i >> 6, c = i & 63u;
        abytes[row][c] = *(const unsigned*)(zr + (size_t)row * 256u + c * 4u);
      }
      const unsigned char* xr = xsb + ((size_t)t * 128u + mh * 64u) * 128u;
      for (unsigned i = tid; i < 2048u; i += 256u) {
        const unsigned row = i >> 5, c = i & 31u;
        abytes[row][64u + c] = *(const unsigned*)(xr + (size_t)row * 128u + c * 4u);
      }
    }
    __syncthreads();
    // ---- MFMA over this wave's K range (24 K-tiles of 32) ----
    f32x4 acc0 = {0.f,0.f,0.f,0.f}, acc1 = {0.f,0.f,0.f,0.f};
    f32x4 acc2 = {0.f,0.f,0.f,0.f}, acc3 = {0.f,0.f,0.f,0.f};
    const int kt0 = (int)wv * 24, kt1 = kt0 + 24;
    for (int kc = kt0; kc < kt1; kc += 4) {
      U4S8 ar0, ar1, ar2, ar3;
      ar0.u = *(const u32x4*)&abytes[ 0 + ln15][kc];
      ar1.u = *(const u32x4*)&abytes[16 + ln15][kc];
      ar2.u = *(const u32x4*)&abytes[32 + ln15][kc];
      ar3.u = *(const u32x4*)&abytes[48 + ln15][kc];
      U4S8 bh[4], blo[4];
#pragma unroll
      for (int j = 0; j < 4; ++j) {
        bh[j].u  = WH[(size_t)(kc + j) * 64u + lane];
        blo[j].u = WL[(size_t)(kc + j) * 64u + lane];
      }
#pragma unroll
      for (int j = 0; j < 4; ++j) {
        const short8 bhj = bh[j].s, blj = blo[j].s;
        auto dosub = [&](unsigned dw, f32x4& ACC) {
          const unsigned by = (dw >> shg) & 0xFFu;
          U4S8 af;
#pragma unroll
          for (int u2 = 0; u2 < 4; ++u2) {
            const unsigned p = (by >> (2 * u2)) & 3u;
            const unsigned qq = (p | (p << 15)) & 0x10001u;
            af.w[u2] = __umul24(qq, 0x3F80u);   // packed bf16 {0,1} pair
          }
          ACC = __builtin_amdgcn_mfma_f32_16x16x32_bf16(af.s, bhj, ACC, 0, 0, 0);
          ACC = __builtin_amdgcn_mfma_f32_16x16x32_bf16(af.s, blj, ACC, 0, 0, 0);
        };
        dosub(ar0.w[j], acc0);
        dosub(ar1.w[j], acc1);
        dosub(ar2.w[j], acc2);
        dosub(ar3.w[j], acc3);
      }
    }
    // ---- cross-wave reduction ----
#pragma unroll
    for (int r = 0; r < 4; ++r) {
      red[wv][ 0 + g4 * 4 + r][ln15] = acc0[r];
      red[wv][16 + g4 * 4 + r][ln15] = acc1[r];
      red[wv][32 + g4 * 4 + r][ln15] = acc2[r];
      red[wv][48 + g4 * 4 + r][ln15] = acc3[r];
    }
    __syncthreads();
    // ---- ALIF state update (thread owns batch row blq, neurons q*4..q*4+3) ----
    {
      unsigned nib = 0u;
#pragma unroll
      for (int jj = 0; jj < 4; ++jj) {
        const unsigned n = q * 4u + (unsigned)jj;
        const float dv = (red[0][blq][n] + red[1][blq][n]) + (red[2][blq][n] + red[3][blq][n]);
        const float vv = __fsub_rn(__fadd_rn(__fmul_rn(0.8f, v[jj]), dv),
                                   __fmul_rn(zf[jj], 0.6f));
        a[jj] = __fadd_rn(__fmul_rn(0.97f, a[jj]), zf[jj]);
        const float th = __fadd_rn(0.6f, __fmul_rn(0.07f, a[jj]));
        const bool znew = vv > th;
        zf[jj] = znew ? 1.0f : 0.0f;
        v[jj] = vv;
        nib |= (znew ? 1u : 0u) << jj;
      }
      zn[blq][q] = (unsigned char)nib;
    }
    __syncthreads();
    if (tid < 64u) {
      const unsigned m16 = (unsigned)zn[tid][0] | ((unsigned)zn[tid][1] << 4) |
                           ((unsigned)zn[tid][2] << 8) | ((unsigned)zn[tid][3] << 12);
      zrow[tid] = (unsigned short)m16;
      *(unsigned short*)(zb + (size_t)((t & 1) ^ 1) * 32768u +
                         (size_t)(mh * 64u + tid) * 256u + ns * 2u) = (unsigned short)m16;
    }
    __syncthreads();
    // ---- per-slice readout partials (z_t @ w_out/w_li over this slice's 16 neurons) ----
    {
      const unsigned m16 = zrow[blq];
      float* pbase = part + ((((size_t)(t & 1) * 2u + mh) * 128u + ns) * 64u + blq) * 36u;
      for (unsigned o = q; o < 33u; o += 4u) {
        const float* wrow = (o < 32u) ? (w_out + (size_t)o * 2048u + ns * 16u)
                                      : (w_li + ns * 16u);
        float s = 0.f;
#pragma unroll
        for (int n = 0; n < 16; ++n) s += (((m16 >> n) & 1u) ? wrow[n] : 0.f);
        pbase[o] = s;
      }
    }
    grid_barrier(bar);
  }
  // ---- final readout accumulate (t = 198) + softmax/critic output ----
  if (wg < 128u) {
    {
      const unsigned pr = (unsigned)(TSTEPS - 1) & 1u;
      if (tid < 132u) {
        const unsigned o = tid >> 2, c = tid & 3u;
        const float* pp = part +
            ((((size_t)pr * 2u + (wg >> 6)) * 128u + c * 32u) * 64u + (wg & 63u)) * 36u + o;
        float s = 0.f;
#pragma unroll 8
        for (unsigned n2 = 0; n2 < 32u; ++n2) s += pp[(size_t)n2 * (64u * 36u)];
        red2[o][c] = s;
      }
      __syncthreads();
      if (tid < 132u && (tid & 3u) == 0u) {
        const unsigned o = tid >> 2;
        const float s = (red2[o][0] + red2[o][1]) + (red2[o][2] + red2[o][3]);
        if (o < 32u) {
          vo = __fadd_rn(__fmul_rn(0.8f, vo), s);
          voMax = fmaxf(voMax, vo);
        } else {
          const float ij = __fadd_rn(lii, s);
          liv = __fadd_rn(liv, __fmul_rn(0.1f, __fsub_rn(ij, liv)));
          lii = __fsub_rn(ij, __fmul_rn(0.2f, ij));
          liMax = fmaxf(liMax, liv);
        }
      }
    }
    if (tid < 132u && (tid & 3u) == 0u) {
      const unsigned o = tid >> 2;
      if (o < 32u) sm[o] = voMax; else sm[32] = liMax;
    }
    __syncthreads();
    if (tid == 0) {
      float mx = sm[0];
      for (int o = 1; o < 32; ++o) mx = fmaxf(mx, sm[o]);
      float ssum = 0.f;
      for (int o = 0; o < 32; ++o) ssum += expf(sm[o] - mx);
      const float inv = 1.0f / ssum;
      for (int o = 0; o < 32; ++o) out[(size_t)wg * 32u + o] = expf(sm[o] - mx) * inv;
      out[4096u + wg] = sm[32];
    }
  }
}

// ---------------- launch ----------------
extern "C" void kernel_launch(void* const* d_in, const int* in_sizes, int n_in,
                              void* d_out, int out_size, void* d_ws, size_t ws_size,
                              hipStream_t stream)
{
  (void)in_sizes; (void)n_in; (void)out_size;
  if (ws_size < (size_t)WS_NEED) return;

  const float* x     = (const float*)d_in[0];
  const float* w_in  = (const float*)d_in[1];
  const float* w_rec = (const float*)d_in[2];
  const float* w_out = (const float*)d_in[3];
  const float* w_li  = (const float*)d_in[4];
  unsigned char* ws  = (unsigned char*)d_ws;

  unsigned*      bar  = (unsigned*)(ws + WS_BAR);
  unsigned char* zbuf = ws + WS_ZB;
  unsigned char* xsb  = ws + WS_XSB;
  float*         part = (float*)(ws + WS_PART);
  u32x4*         wf   = (u32x4*)(ws + WS_WF);

  hipMemsetAsync(bar, 0, 64, stream);
  hipMemsetAsync(zbuf, 0, 65536, stream);
  k_encode<<<dim3(128), dim3(1024), 0, stream>>>(x, xsb);
  k_prep<<<dim3(3072), dim3(256), 0, stream>>>(w_rec, w_in, wf);
  k_main<<<dim3(256), dim3(256), 0, stream>>>(wf, xsb, zbuf, part, w_out, w_li, bar,
                                              (float*)d_out);
}

// Round 2
// 2686.100 us; speedup vs baseline: 4.1838x; 4.1838x over previous
//
#include <hip/hip_runtime.h>
#include <cstdint>
#include <cstddef>

typedef __attribute__((ext_vector_type(8))) short short8;
typedef __attribute__((ext_vector_type(4))) float f32x4;
typedef __attribute__((ext_vector_type(4))) unsigned int u32x4;

union U4S8 { u32x4 u; short8 s; unsigned w[4]; };

#define TSTEPS 199
#define NWG    256u

#define WF_PLANE 786432u    // u32x4 per main plane (128 slices x 96 kt x 64 lanes)
#define WR_BASE  1572864u   // u32x4 index where readout frags start
#define WR_PLANE 12288u     // 3 slices x 64 kt x 64 lanes

// ---- workspace layout (bytes) ----
#define WS_BAR  0u           // tree barrier counters (monotonic), 4 KB
#define WS_ZB   4096u        // 2 buf x 2 mh x 64 row x 128 ns u32  = 128 KB
#define WS_FIN  135168u      // 128 x 32 f32 voMax                  = 16 KB
#define WS_XSB  151552u      // 199 x 128 x 128 B encoder bits
#define WS_WF   3411968u     // (1572864 + 2*12288) x 16 B fragments
#define WS_NEED 28971008u

// ---------------- encoder: constant-current LIF -> spike bit rows ----------------
extern "C" __global__ __launch_bounds__(1024) void k_encode(
    const float* __restrict__ x, unsigned char* __restrict__ xsb)
{
  const int b = blockIdx.x;
  const int tid = threadIdx.x;
  const float xv = (tid < 512) ? x[b * 512 + tid] : x[b * 512 + tid - 512];
  const float I = (tid < 512) ? fmaxf(__fmul_rn(50.0f, xv), 0.0f)
                              : fmaxf(__fmul_rn(-50.0f, xv), 0.0f);
  float v = 0.0f;
  unsigned long long* dst =
      (unsigned long long*)(xsb + (size_t)b * 128u + (size_t)(tid >> 6) * 8u);
  for (int t = 0; t < TSTEPS; ++t) {
    v = __fadd_rn(v, __fmul_rn(0.1f, __fsub_rn(I, v)));
    const bool z = v > 1.0f;
    if (z) v = 0.0f;
    const unsigned long long m = __ballot(z ? 1 : 0);
    if ((tid & 63) == 0) dst[(size_t)t * 2048u] = m;
  }
}

// ---------------- weight prep: hi/lo bf16 split into MFMA-fragment order ----------------
__device__ __forceinline__ unsigned bf16rne(float f) {
  const unsigned u = __float_as_uint(f);
  return ((u + 0x7FFFu + ((u >> 16) & 1u)) >> 16) & 0xFFFFu;
}

extern "C" __global__ __launch_bounds__(256) void k_prep(
    const float* __restrict__ w_rec, const float* __restrict__ w_in,
    const float* __restrict__ w_out, const float* __restrict__ w_li,
    u32x4* __restrict__ wf)
{
  const unsigned idx  = blockIdx.x * 256u + threadIdx.x;
  const unsigned lane = idx & 63u;
  if (idx < 786432u) {
    // main fragments: slice ns (128), kt (96), lane
    const unsigned kt = (idx >> 6) % 96u;
    const unsigned ns = idx / 6144u;
    const unsigned j  = ns * 16u + (lane & 15u);
    const unsigned k0 = kt * 32u + (lane >> 4) * 8u;
    unsigned hi[4], lo[4];
#pragma unroll
    for (int u2 = 0; u2 < 4; ++u2) {
      unsigned hb[2], lb[2];
#pragma unroll
      for (int c = 0; c < 2; ++c) {
        const unsigned k = k0 + 2u * (unsigned)u2 + (unsigned)c;
        float w;
        if (k < 2048u) w = (k == j) ? 0.0f : w_rec[(size_t)j * 2048u + k];
        else           w = w_in[(size_t)j * 1024u + (k - 2048u)];
        const unsigned h = bf16rne(w);
        const float hvf = __uint_as_float(h << 16);
        const unsigned l = bf16rne(__fsub_rn(w, hvf));
        hb[c] = h; lb[c] = l;
      }
      hi[u2] = hb[0] | (hb[1] << 16);
      lo[u2] = lb[0] | (lb[1] << 16);
    }
    u32x4 vh, vl;
    vh[0]=hi[0]; vh[1]=hi[1]; vh[2]=hi[2]; vh[3]=hi[3];
    vl[0]=lo[0]; vl[1]=lo[1]; vl[2]=lo[2]; vl[3]=lo[3];
    wf[idx] = vh;
    wf[idx + WF_PLANE] = vl;
  } else if (idx < 786432u + 12288u) {
    // readout fragments (hi plane only): slice nsr (3), kt (64), lane
    const unsigned r   = idx - 786432u;
    const unsigned kt  = (r >> 6) & 63u;
    const unsigned nsr = r >> 12;
    const unsigned o   = nsr * 16u + (lane & 15u);
    const unsigned k0  = kt * 32u + (lane >> 4) * 8u;
    unsigned hi[4];
#pragma unroll
    for (int u2 = 0; u2 < 4; ++u2) {
      unsigned hb[2];
#pragma unroll
      for (int c = 0; c < 2; ++c) {
        const unsigned k = k0 + 2u * (unsigned)u2 + (unsigned)c;
        float w = 0.0f;
        if (o < 32u)       w = w_out[(size_t)o * 2048u + k];
        else if (o == 32u) w = w_li[k];
        hb[c] = bf16rne(w);
      }
      hi[u2] = hb[0] | (hb[1] << 16);
    }
    u32x4 vh; vh[0]=hi[0]; vh[1]=hi[1]; vh[2]=hi[2]; vh[3]=hi[3];
    wf[WR_BASE + r] = vh;
  }
}

// ---------------- fence-free monotonic tree barrier ----------------
__device__ __forceinline__ void grid_barrier(unsigned* bar, unsigned tgt)
{
  __syncthreads();   // each wave drains its own vmcnt before s_barrier
  if (threadIdx.x == 0) {
    unsigned* grp  = bar + (blockIdx.x >> 4) * 16u;   // 64B-spaced group counters
    unsigned* root = bar + 256u;
    unsigned prev = __hip_atomic_fetch_add(grp, 1u, __ATOMIC_RELAXED, __HIP_MEMORY_SCOPE_AGENT);
    if ((prev & 15u) == 15u) {
      unsigned p2 = __hip_atomic_fetch_add(root, 1u, __ATOMIC_RELAXED, __HIP_MEMORY_SCOPE_AGENT);
      if ((p2 & 15u) == 15u) {
        __hip_atomic_store(bar + 272u, tgt, __ATOMIC_RELAXED, __HIP_MEMORY_SCOPE_AGENT);
      }
    }
    while (__hip_atomic_load(bar + 272u, __ATOMIC_RELAXED, __HIP_MEMORY_SCOPE_AGENT) < tgt) {
      __builtin_amdgcn_s_sleep(2);
    }
    asm volatile("" ::: "memory");
  }
  __syncthreads();
}

// ---------------- main persistent ALIF kernel ----------------
// grid 256: wg = mh(2) x ns(128 slices of 16 neurons); 512 threads = 8 waves K-split
extern "C" __global__ __launch_bounds__(512) void k_main(
    const u32x4* __restrict__ wf,
    const unsigned char* __restrict__ xsb,
    unsigned* __restrict__ zb,
    unsigned* __restrict__ bar,
    unsigned* __restrict__ fin,
    float* __restrict__ out)
{
  __shared__ unsigned abytes[64][100];   // z bits cols 0..63, xs bits cols 64..95
  __shared__ float red[8][64][17];
  __shared__ unsigned char zn[64][4];
  __shared__ float pad_lds[6000];        // force 1 wg/CU (LDS > 80 KB)

  const unsigned tid  = threadIdx.x;
  const unsigned wg   = blockIdx.x;
  const unsigned mh   = wg >> 7;
  const unsigned ns   = wg & 127u;
  const unsigned wv   = tid >> 6;        // 0..7
  const unsigned lane = tid & 63u;
  const unsigned ln15 = lane & 15u;
  const unsigned g4   = lane >> 4;
  const unsigned shg  = g4 * 8u;
  const unsigned blq  = tid & 63u;       // owned batch row (update phases, tid<256)
  const unsigned q    = tid >> 6;        // owned neuron/output quad (update phases)
  const bool     upd  = tid < 256u;
  const bool     dual = ns < 3u;

  if (tid == 0) ((volatile float*)pad_lds)[0] = 0.f;

  const u32x4* WH = wf + (size_t)ns * 6144u;
  const u32x4* WL = wf + WF_PLANE + (size_t)ns * 6144u;
  const u32x4* RH = wf + WR_BASE + (size_t)ns * 4096u;

  float v[4]  = {0,0,0,0}, a[4] = {0,0,0,0}, zf[4] = {0,0,0,0};
  float vo[4] = {0,0,0,0}, voMax[4] = {0,0,0,0};
  float liv = 0.f, lii = 0.f, liMax = 0.f;

  auto stage_z = [&](unsigned buf) {
    const unsigned base = (buf * 2u + mh) * 64u * 128u;
    for (unsigned i = tid; i < 4096u; i += 512u) {
      const unsigned row = i >> 6, np = i & 63u;
      const unsigned long long vz = __hip_atomic_load(
          (const unsigned long long*)(zb + base + row * 128u + np * 2u),
          __ATOMIC_RELAXED, __HIP_MEMORY_SCOPE_AGENT);
      abytes[row][np] = (unsigned)(vz & 0xFFFFu) | (unsigned)(((vz >> 32) & 0xFFFFu) << 16);
    }
  };

  auto dosub2 = [&](unsigned dw, const short8& bhj, const short8& blj, f32x4& ACC) {
    const unsigned by = (dw >> shg) & 0xFFu;
    U4S8 af;
#pragma unroll
    for (int u2 = 0; u2 < 4; ++u2) {
      const unsigned p = (by >> (2 * u2)) & 3u;
      af.w[u2] = ((p | (p << 15)) & 0x10001u) * 0x3F80u;
    }
    ACC = __builtin_amdgcn_mfma_f32_16x16x32_bf16(af.s, bhj, ACC, 0, 0, 0);
    ACC = __builtin_amdgcn_mfma_f32_16x16x32_bf16(af.s, blj, ACC, 0, 0, 0);
  };
  auto dosub1 = [&](unsigned dw, const short8& bhj, f32x4& ACC) {
    const unsigned by = (dw >> shg) & 0xFFu;
    U4S8 af;
#pragma unroll
    for (int u2 = 0; u2 < 4; ++u2) {
      const unsigned p = (by >> (2 * u2)) & 3u;
      af.w[u2] = ((p | (p << 15)) & 0x10001u) * 0x3F80u;
    }
    ACC = __builtin_amdgcn_mfma_f32_16x16x32_bf16(af.s, bhj, ACC, 0, 0, 0);
  };

  auto readout_pass = [&]() {
    f32x4 r0 = {0,0,0,0}, r1 = {0,0,0,0}, r2 = {0,0,0,0}, r3 = {0,0,0,0};
    const int kb = (int)wv * 8;
    for (int kc = kb; kc < kb + 8; kc += 4) {
      U4S8 ar0, ar1, ar2, ar3;
      ar0.u = *(const u32x4*)&abytes[ 0 + ln15][kc];
      ar1.u = *(const u32x4*)&abytes[16 + ln15][kc];
      ar2.u = *(const u32x4*)&abytes[32 + ln15][kc];
      ar3.u = *(const u32x4*)&abytes[48 + ln15][kc];
      U4S8 bh[4];
#pragma unroll
      for (int j = 0; j < 4; ++j) bh[j].u = RH[(size_t)(kc + j) * 64u + lane];
#pragma unroll
      for (int j = 0; j < 4; ++j) {
        const short8 bhj = bh[j].s;
        dosub1(ar0.w[j], bhj, r0);
        dosub1(ar1.w[j], bhj, r1);
        dosub1(ar2.w[j], bhj, r2);
        dosub1(ar3.w[j], bhj, r3);
      }
    }
#pragma unroll
    for (int r = 0; r < 4; ++r) {
      red[wv][ 0 + g4 * 4 + r][ln15] = r0[r];
      red[wv][16 + g4 * 4 + r][ln15] = r1[r];
      red[wv][32 + g4 * 4 + r][ln15] = r2[r];
      red[wv][48 + g4 * 4 + r][ln15] = r3[r];
    }
    __syncthreads();
    if (upd) {
      if (ns < 2u) {
#pragma unroll
        for (int jj = 0; jj < 4; ++jj) {
          const unsigned n = q * 4u + (unsigned)jj;
          float s = ((red[0][blq][n] + red[1][blq][n]) + (red[2][blq][n] + red[3][blq][n]))
                  + ((red[4][blq][n] + red[5][blq][n]) + (red[6][blq][n] + red[7][blq][n]));
          vo[jj] = __fadd_rn(__fmul_rn(0.8f, vo[jj]), s);
          voMax[jj] = fmaxf(voMax[jj], vo[jj]);
        }
      } else if (q == 0u) {
        float s = ((red[0][blq][0] + red[1][blq][0]) + (red[2][blq][0] + red[3][blq][0]))
                + ((red[4][blq][0] + red[5][blq][0]) + (red[6][blq][0] + red[7][blq][0]));
        const float ij = __fadd_rn(lii, s);
        liv = __fadd_rn(liv, __fmul_rn(0.1f, __fsub_rn(ij, liv)));
        lii = __fsub_rn(ij, __fmul_rn(0.2f, ij));
        liMax = fmaxf(liMax, liv);
      }
    }
    __syncthreads();
  };

  for (int t = 0; t < TSTEPS; ++t) {
    const unsigned buf = (unsigned)t & 1u;
    // ---- stage A bits: z_t (agent loads, bypass L2) + xs_t (cached) ----
    stage_z(buf);
    {
      const unsigned char* xr = xsb + ((size_t)t * 128u + mh * 64u) * 128u;
      for (unsigned i = tid; i < 2048u; i += 512u) {
        const unsigned row = i >> 5, c = i & 31u;
        abytes[row][64u + c] = *(const unsigned*)(xr + (size_t)row * 128u + c * 4u);
      }
    }
    __syncthreads();

    // ---- dual-duty wgs: readout of z_t (t>=1), overlapped in-register ----
    if (dual && t > 0) readout_pass();

    // ---- main MFMA over this wave's 12 K-tiles ----
    f32x4 acc0 = {0,0,0,0}, acc1 = {0,0,0,0}, acc2 = {0,0,0,0}, acc3 = {0,0,0,0};
    const int kt0 = (int)wv * 12;
    for (int kc = kt0; kc < kt0 + 12; kc += 4) {
      U4S8 ar0, ar1, ar2, ar3;
      ar0.u = *(const u32x4*)&abytes[ 0 + ln15][kc];
      ar1.u = *(const u32x4*)&abytes[16 + ln15][kc];
      ar2.u = *(const u32x4*)&abytes[32 + ln15][kc];
      ar3.u = *(const u32x4*)&abytes[48 + ln15][kc];
      U4S8 bh[4], blo[4];
#pragma unroll
      for (int j = 0; j < 4; ++j) {
        bh[j].u  = WH[(size_t)(kc + j) * 64u + lane];
        blo[j].u = WL[(size_t)(kc + j) * 64u + lane];
      }
#pragma unroll
      for (int j = 0; j < 4; ++j) {
        const short8 bhj = bh[j].s, blj = blo[j].s;
        dosub2(ar0.w[j], bhj, blj, acc0);
        dosub2(ar1.w[j], bhj, blj, acc1);
        dosub2(ar2.w[j], bhj, blj, acc2);
        dosub2(ar3.w[j], bhj, blj, acc3);
      }
    }
#pragma unroll
    for (int r = 0; r < 4; ++r) {
      red[wv][ 0 + g4 * 4 + r][ln15] = acc0[r];
      red[wv][16 + g4 * 4 + r][ln15] = acc1[r];
      red[wv][32 + g4 * 4 + r][ln15] = acc2[r];
      red[wv][48 + g4 * 4 + r][ln15] = acc3[r];
    }
    __syncthreads();
    // ---- ALIF state update ----
    if (upd) {
      unsigned nib = 0u;
#pragma unroll
      for (int jj = 0; jj < 4; ++jj) {
        const unsigned n = q * 4u + (unsigned)jj;
        const float dv = ((red[0][blq][n] + red[1][blq][n]) + (red[2][blq][n] + red[3][blq][n]))
                       + ((red[4][blq][n] + red[5][blq][n]) + (red[6][blq][n] + red[7][blq][n]));
        const float vv = __fsub_rn(__fadd_rn(__fmul_rn(0.8f, v[jj]), dv),
                                   __fmul_rn(zf[jj], 0.6f));
        a[jj] = __fadd_rn(__fmul_rn(0.97f, a[jj]), zf[jj]);
        const float th = __fadd_rn(0.6f, __fmul_rn(0.07f, a[jj]));
        const bool znew = vv > th;
        zf[jj] = znew ? 1.0f : 0.0f;
        v[jj] = vv;
        nib |= (znew ? 1u : 0u) << jj;
      }
      zn[blq][q] = (unsigned char)nib;
    }
    __syncthreads();
    // ---- publish z_{t+1} bits (agent store, write-through) ----
    if (tid < 64u) {
      const unsigned m16 = (unsigned)zn[tid][0] | ((unsigned)zn[tid][1] << 4) |
                           ((unsigned)zn[tid][2] << 8) | ((unsigned)zn[tid][3] << 12);
      const unsigned nb = buf ^ 1u;
      __hip_atomic_store(zb + ((nb * 2u + mh) * 64u + tid) * 128u + ns, m16,
                         __ATOMIC_RELAXED, __HIP_MEMORY_SCOPE_AGENT);
    }
    grid_barrier(bar, (unsigned)t + 1u);
  }

  // ---- post-loop: readout of z_199 + publish results ----
  if (dual) {
    stage_z(1u);
    __syncthreads();
    readout_pass();
    if (ns < 2u && upd) {
#pragma unroll
      for (int jj = 0; jj < 4; ++jj) {
        __hip_atomic_store(fin + ((size_t)mh * 64u + blq) * 32u + ns * 16u + q * 4u + (unsigned)jj,
                           __float_as_uint(voMax[jj]),
                           __ATOMIC_RELAXED, __HIP_MEMORY_SCOPE_AGENT);
      }
    }
    if (ns == 2u && tid < 64u) {
      out[4096u + mh * 64u + tid] = liMax;   // plain store to d_out (read after kernel end)
    }
  }
  grid_barrier(bar, (unsigned)TSTEPS + 1u);

  // ---- wg0: softmax over voMax ----
  if (wg == 0u && tid < 128u) {
    float vals[32];
#pragma unroll
    for (int o = 0; o < 32; ++o)
      vals[o] = __uint_as_float(__hip_atomic_load(fin + (size_t)tid * 32u + o,
                                                  __ATOMIC_RELAXED, __HIP_MEMORY_SCOPE_AGENT));
    float mx = vals[0];
#pragma unroll
    for (int o = 1; o < 32; ++o) mx = fmaxf(mx, vals[o]);
    float ssum = 0.f;
#pragma unroll
    for (int o = 0; o < 32; ++o) ssum += expf(vals[o] - mx);
    const float inv = 1.0f / ssum;
#pragma unroll
    for (int o = 0; o < 32; ++o) out[(size_t)tid * 32u + o] = expf(vals[o] - mx) * inv;
  }
}

// ---------------- launch ----------------
extern "C" void kernel_launch(void* const* d_in, const int* in_sizes, int n_in,
                              void* d_out, int out_size, void* d_ws, size_t ws_size,
                              hipStream_t stream)
{
  (void)in_sizes; (void)n_in; (void)out_size;
  if (ws_size < (size_t)WS_NEED) return;

  const float* x     = (const float*)d_in[0];
  const float* w_in  = (const float*)d_in[1];
  const float* w_rec = (const float*)d_in[2];
  const float* w_out = (const float*)d_in[3];
  const float* w_li  = (const float*)d_in[4];
  unsigned char* ws  = (unsigned char*)d_ws;

  unsigned*      bar  = (unsigned*)(ws + WS_BAR);
  unsigned*      zb   = (unsigned*)(ws + WS_ZB);
  unsigned*      fin  = (unsigned*)(ws + WS_FIN);
  unsigned char* xsb  = ws + WS_XSB;
  u32x4*         wf   = (u32x4*)(ws + WS_WF);

  hipMemsetAsync(bar, 0, 4096, stream);
  hipMemsetAsync(zb, 0, 131072, stream);
  k_encode<<<dim3(128), dim3(1024), 0, stream>>>(x, xsb);
  k_prep<<<dim3(3120), dim3(256), 0, stream>>>(w_rec, w_in, w_out, w_li, wf);
  k_main<<<dim3(256), dim3(512), 0, stream>>>(wf, xsb, zb, bar, fin, (float*)d_out);
}

// Round 3
// 2048.420 us; speedup vs baseline: 5.4862x; 1.3113x over previous
//
#include <hip/hip_runtime.h>
#include <cstdint>
#include <cstddef>

typedef __attribute__((ext_vector_type(8))) short short8;
typedef __attribute__((ext_vector_type(4))) float f32x4;
typedef __attribute__((ext_vector_type(4))) unsigned int u32x4;

union U4S8 { u32x4 u; short8 s; unsigned w[4]; };

#define TSTEPS 199
#define NWG    256u

#define WF_PLANE 786432u    // u32x4 per main plane (128 slices x 96 kt x 64 lanes)
#define WR_BASE  1572864u   // u32x4 index where readout frags start
#define WR_PLANE 12288u     // 3 slices x 64 kt x 64 lanes (hi plane; lo follows)

// ---- workspace layout (bytes) ----
#define WS_BAR  0u           // tree barrier counters (monotonic), 4 KB
#define WS_ZB   4096u        // 2 buf x 2 mh x 64 row x 128 ns u32  = 128 KB
#define WS_FIN  135168u      // 128 x 32 f32 voMax                  = 16 KB
#define WS_XSB  151552u      // 199 x 128 x 128 B encoder bits
#define WS_WF   3411968u     // (1572864 + 2*12288) x 16 B fragments
#define WS_NEED 28971008u

#define AT_RLX __ATOMIC_RELAXED
#define SC_AGT __HIP_MEMORY_SCOPE_AGENT

// ---------------- encoder: constant-current LIF -> spike bit rows ----------------
extern "C" __global__ __launch_bounds__(1024) void k_encode(
    const float* __restrict__ x, unsigned char* __restrict__ xsb)
{
  const int b = blockIdx.x;
  const int tid = threadIdx.x;
  const float xv = (tid < 512) ? x[b * 512 + tid] : x[b * 512 + tid - 512];
  const float I = (tid < 512) ? fmaxf(__fmul_rn(50.0f, xv), 0.0f)
                              : fmaxf(__fmul_rn(-50.0f, xv), 0.0f);
  float v = 0.0f;
  unsigned long long* dst =
      (unsigned long long*)(xsb + (size_t)b * 128u + (size_t)(tid >> 6) * 8u);
  for (int t = 0; t < TSTEPS; ++t) {
    v = __fadd_rn(v, __fmul_rn(0.1f, __fsub_rn(I, v)));
    const bool z = v > 1.0f;
    if (z) v = 0.0f;
    const unsigned long long m = __ballot(z ? 1 : 0);
    if ((tid & 63) == 0) dst[(size_t)t * 2048u] = m;
  }
}

// ---------------- weight prep: hi/lo bf16 split into MFMA-fragment order ----------------
__device__ __forceinline__ unsigned bf16rne(float f) {
  const unsigned u = __float_as_uint(f);
  return ((u + 0x7FFFu + ((u >> 16) & 1u)) >> 16) & 0xFFFFu;
}

extern "C" __global__ __launch_bounds__(256) void k_prep(
    const float* __restrict__ w_rec, const float* __restrict__ w_in,
    const float* __restrict__ w_out, const float* __restrict__ w_li,
    u32x4* __restrict__ wf)
{
  const unsigned idx  = blockIdx.x * 256u + threadIdx.x;
  const unsigned lane = idx & 63u;
  if (idx < 786432u) {
    const unsigned kt = (idx >> 6) % 96u;
    const unsigned ns = idx / 6144u;
    const unsigned j  = ns * 16u + (lane & 15u);
    const unsigned k0 = kt * 32u + (lane >> 4) * 8u;
    unsigned hi[4], lo[4];
#pragma unroll
    for (int u2 = 0; u2 < 4; ++u2) {
      unsigned hb[2], lb[2];
#pragma unroll
      for (int c = 0; c < 2; ++c) {
        const unsigned k = k0 + 2u * (unsigned)u2 + (unsigned)c;
        float w;
        if (k < 2048u) w = (k == j) ? 0.0f : w_rec[(size_t)j * 2048u + k];
        else           w = w_in[(size_t)j * 1024u + (k - 2048u)];
        const unsigned h = bf16rne(w);
        const float hvf = __uint_as_float(h << 16);
        const unsigned l = bf16rne(__fsub_rn(w, hvf));
        hb[c] = h; lb[c] = l;
      }
      hi[u2] = hb[0] | (hb[1] << 16);
      lo[u2] = lb[0] | (lb[1] << 16);
    }
    u32x4 vh, vl;
    vh[0]=hi[0]; vh[1]=hi[1]; vh[2]=hi[2]; vh[3]=hi[3];
    vl[0]=lo[0]; vl[1]=lo[1]; vl[2]=lo[2]; vl[3]=lo[3];
    wf[idx] = vh;
    wf[idx + WF_PLANE] = vl;
  } else if (idx < 786432u + 12288u) {
    // readout fragments hi+lo: slice nsr (3), kt (64), lane
    const unsigned r   = idx - 786432u;
    const unsigned kt  = (r >> 6) & 63u;
    const unsigned nsr = r >> 12;
    const unsigned o   = nsr * 16u + (lane & 15u);
    const unsigned k0  = kt * 32u + (lane >> 4) * 8u;
    unsigned hi[4], lo[4];
#pragma unroll
    for (int u2 = 0; u2 < 4; ++u2) {
      unsigned hb[2], lb[2];
#pragma unroll
      for (int c = 0; c < 2; ++c) {
        const unsigned k = k0 + 2u * (unsigned)u2 + (unsigned)c;
        float w = 0.0f;
        if (o < 32u)       w = w_out[(size_t)o * 2048u + k];
        else if (o == 32u) w = w_li[k];
        const unsigned h = bf16rne(w);
        const float hvf = __uint_as_float(h << 16);
        hb[c] = h;
        lb[c] = bf16rne(__fsub_rn(w, hvf));
      }
      hi[u2] = hb[0] | (hb[1] << 16);
      lo[u2] = lb[0] | (lb[1] << 16);
    }
    u32x4 vh, vl;
    vh[0]=hi[0]; vh[1]=hi[1]; vh[2]=hi[2]; vh[3]=hi[3];
    vl[0]=lo[0]; vl[1]=lo[1]; vl[2]=lo[2]; vl[3]=lo[3];
    wf[WR_BASE + r] = vh;
    wf[WR_BASE + WR_PLANE + r] = vl;
  }
}

// ---------------- decoupled monotonic tree barrier ----------------
__device__ __forceinline__ void bar_arrive(unsigned* bar)
{
  __syncthreads();   // drain this wg's vmem (zb publish) before signaling
  if (threadIdx.x == 0) {
    unsigned* grp = bar + (blockIdx.x >> 4) * 16u;
    const unsigned prev = __hip_atomic_fetch_add(grp, 1u, AT_RLX, SC_AGT);
    if ((prev & 15u) == 15u) {
      const unsigned p2 = __hip_atomic_fetch_add(bar + 256u, 1u, AT_RLX, SC_AGT);
      if ((p2 & 15u) == 15u) {
        __hip_atomic_store(bar + 272u, (p2 >> 4) + 1u, AT_RLX, SC_AGT);
      }
    }
  }
}

__device__ __forceinline__ void bar_wait(unsigned* bar, unsigned tgt)
{
  if (threadIdx.x == 0) {
    while (__hip_atomic_load(bar + 272u, AT_RLX, SC_AGT) < tgt) {
      __builtin_amdgcn_s_sleep(1);
    }
    asm volatile("" ::: "memory");
  }
  __syncthreads();
}

// ---------------- main persistent ALIF kernel ----------------
// grid 256: wg = mh(2) x ns(128 slices of 16 neurons); 512 threads = 8 waves
// per step: z-part (64 kt) on critical path; xs-part (32 kt) + readout in barrier shadow
extern "C" __global__ __launch_bounds__(512) void k_main(
    const u32x4* __restrict__ wf,
    const unsigned char* __restrict__ xsb,
    unsigned* __restrict__ zb,
    unsigned* __restrict__ bar,
    unsigned* __restrict__ fin,
    float* __restrict__ out)
{
  __shared__ unsigned abytes[64][100];   // z bits cols 0..63, xs bits cols 64..95
  __shared__ float red[8][64][17];
  __shared__ unsigned char zn[64][4];
  __shared__ float pad_lds[6000];        // force 1 wg/CU

  const unsigned tid  = threadIdx.x;
  const unsigned wg   = blockIdx.x;
  const unsigned mh   = wg >> 7;
  const unsigned ns   = wg & 127u;
  const unsigned wv   = tid >> 6;
  const unsigned lane = tid & 63u;
  const unsigned ln15 = lane & 15u;
  const unsigned g4   = lane >> 4;
  const unsigned shg  = g4 * 8u;
  const unsigned blq  = tid & 63u;
  const unsigned q    = tid >> 6;
  const bool     upd  = tid < 256u;
  const bool     dual = ns < 3u;

  if (tid == 0) ((volatile float*)pad_lds)[0] = 0.f;

  const u32x4* WH = wf + (size_t)ns * 6144u;
  const u32x4* WL = wf + WF_PLANE + (size_t)ns * 6144u;
  const u32x4* RH = wf + WR_BASE + (size_t)ns * 4096u;
  const u32x4* RL = wf + WR_BASE + WR_PLANE + (size_t)ns * 4096u;

  float v[4]  = {0,0,0,0}, a[4] = {0,0,0,0}, zf[4] = {0,0,0,0};
  float vo[4] = {0,0,0,0}, voMax[4] = {0,0,0,0};
  float liv = 0.f, lii = 0.f, liMax = 0.f;

  f32x4 accX0 = {0,0,0,0}, accX1 = {0,0,0,0}, accX2 = {0,0,0,0}, accX3 = {0,0,0,0};
  U4S8 bhA[4], blA[4];   // prefetched z-part weight group A (kt kb..kb+3)

  auto stage_z = [&](unsigned buf) {
    const unsigned base = (buf * 2u + mh) * 64u * 128u;
    for (unsigned i = tid; i < 4096u; i += 512u) {
      const unsigned row = i >> 6, np = i & 63u;
      const unsigned long long vz = __hip_atomic_load(
          (const unsigned long long*)(zb + base + row * 128u + np * 2u),
          AT_RLX, SC_AGT);
      abytes[row][np] = (unsigned)(vz & 0xFFFFu) | (unsigned)(((vz >> 32) & 0xFFFFu) << 16);
    }
  };

  auto stage_xs = [&](int t) {
    const unsigned char* xr = xsb + ((size_t)t * 128u + mh * 64u) * 128u;
    for (unsigned i = tid; i < 2048u; i += 512u) {
      const unsigned row = i >> 5, c = i & 31u;
      abytes[row][64u + c] = *(const unsigned*)(xr + (size_t)row * 128u + c * 4u);
    }
  };

  auto dosub2 = [&](unsigned dw, const short8& bhj, const short8& blj, f32x4& ACC) {
    const unsigned by = (dw >> shg) & 0xFFu;
    U4S8 af;
#pragma unroll
    for (int u2 = 0; u2 < 4; ++u2) {
      const unsigned p = (by >> (2 * u2)) & 3u;
      af.w[u2] = ((p | (p << 15)) & 0x10001u) * 0x3F80u;
    }
    ACC = __builtin_amdgcn_mfma_f32_16x16x32_bf16(af.s, bhj, ACC, 0, 0, 0);
    ACC = __builtin_amdgcn_mfma_f32_16x16x32_bf16(af.s, blj, ACC, 0, 0, 0);
  };

  auto prefetchA = [&]() {
    const int kb = (int)wv * 8;
#pragma unroll
    for (int j = 0; j < 4; ++j) {
      bhA[j].u = WH[(size_t)(kb + j) * 64u + lane];
      blA[j].u = WL[(size_t)(kb + j) * 64u + lane];
    }
  };

  auto compute_accX = [&]() {   // xs-part: kt 64 + wv*4 .. +4
    accX0 = {0,0,0,0}; accX1 = {0,0,0,0}; accX2 = {0,0,0,0}; accX3 = {0,0,0,0};
    const int kb = 64 + (int)wv * 4;
    U4S8 bh[4], bl[4];
#pragma unroll
    for (int j = 0; j < 4; ++j) {
      bh[j].u = WH[(size_t)(kb + j) * 64u + lane];
      bl[j].u = WL[(size_t)(kb + j) * 64u + lane];
    }
    U4S8 a0, a1, a2, a3;
    a0.u = *(const u32x4*)&abytes[ 0 + ln15][kb];
    a1.u = *(const u32x4*)&abytes[16 + ln15][kb];
    a2.u = *(const u32x4*)&abytes[32 + ln15][kb];
    a3.u = *(const u32x4*)&abytes[48 + ln15][kb];
#pragma unroll
    for (int j = 0; j < 4; ++j) {
      dosub2(a0.w[j], bh[j].s, bl[j].s, accX0);
      dosub2(a1.w[j], bh[j].s, bl[j].s, accX1);
      dosub2(a2.w[j], bh[j].s, bl[j].s, accX2);
      dosub2(a3.w[j], bh[j].s, bl[j].s, accX3);
    }
  };

  auto readout_pass = [&]() {   // hi+lo readout of z currently in abytes cols 0..63
    f32x4 r0 = {0,0,0,0}, r1 = {0,0,0,0}, r2 = {0,0,0,0}, r3 = {0,0,0,0};
    const int kb = (int)wv * 8;
#pragma unroll
    for (int kc = 0; kc < 8; kc += 4) {
      U4S8 ar0, ar1, ar2, ar3;
      ar0.u = *(const u32x4*)&abytes[ 0 + ln15][kb + kc];
      ar1.u = *(const u32x4*)&abytes[16 + ln15][kb + kc];
      ar2.u = *(const u32x4*)&abytes[32 + ln15][kb + kc];
      ar3.u = *(const u32x4*)&abytes[48 + ln15][kb + kc];
      U4S8 bh[4], bl[4];
#pragma unroll
      for (int j = 0; j < 4; ++j) {
        bh[j].u = RH[(size_t)(kb + kc + j) * 64u + lane];
        bl[j].u = RL[(size_t)(kb + kc + j) * 64u + lane];
      }
#pragma unroll
      for (int j = 0; j < 4; ++j) {
        dosub2(ar0.w[j], bh[j].s, bl[j].s, r0);
        dosub2(ar1.w[j], bh[j].s, bl[j].s, r1);
        dosub2(ar2.w[j], bh[j].s, bl[j].s, r2);
        dosub2(ar3.w[j], bh[j].s, bl[j].s, r3);
      }
    }
#pragma unroll
    for (int r = 0; r < 4; ++r) {
      red[wv][ 0 + g4 * 4 + r][ln15] = r0[r];
      red[wv][16 + g4 * 4 + r][ln15] = r1[r];
      red[wv][32 + g4 * 4 + r][ln15] = r2[r];
      red[wv][48 + g4 * 4 + r][ln15] = r3[r];
    }
    __syncthreads();
    if (upd) {
      if (ns < 2u) {
#pragma unroll
        for (int jj = 0; jj < 4; ++jj) {
          const unsigned n = q * 4u + (unsigned)jj;
          float s = ((red[0][blq][n] + red[1][blq][n]) + (red[2][blq][n] + red[3][blq][n]))
                  + ((red[4][blq][n] + red[5][blq][n]) + (red[6][blq][n] + red[7][blq][n]));
          vo[jj] = __fadd_rn(__fmul_rn(0.8f, vo[jj]), s);
          voMax[jj] = fmaxf(voMax[jj], vo[jj]);
        }
      } else if (q == 0u) {
        float s = ((red[0][blq][0] + red[1][blq][0]) + (red[2][blq][0] + red[3][blq][0]))
                + ((red[4][blq][0] + red[5][blq][0]) + (red[6][blq][0] + red[7][blq][0]));
        const float ij = __fadd_rn(lii, s);
        liv = __fadd_rn(liv, __fmul_rn(0.1f, __fsub_rn(ij, liv)));
        lii = __fsub_rn(ij, __fmul_rn(0.2f, ij));
        liMax = fmaxf(liMax, liv);
      }
    }
    __syncthreads();
  };

  // ---- prologue: xs_0 staged + accX(t=0) + weight group A prefetch ----
  stage_xs(0);
  __syncthreads();
  compute_accX();
  prefetchA();

  for (int t = 0; t < TSTEPS; ++t) {
    if (t > 0) bar_wait(bar, (unsigned)t);
    stage_z((unsigned)t & 1u);
    __syncthreads();

    // ---- z-part MFMA (64 kt; this wave: kb..kb+8), acc starts at xs contribution ----
    {
      const int kb = (int)wv * 8;
      U4S8 bhB[4], blB[4];
#pragma unroll
      for (int j = 0; j < 4; ++j) {
        bhB[j].u = WH[(size_t)(kb + 4 + j) * 64u + lane];
        blB[j].u = WL[(size_t)(kb + 4 + j) * 64u + lane];
      }
      U4S8 a0, a1, a2, a3;
      a0.u = *(const u32x4*)&abytes[ 0 + ln15][kb];
      a1.u = *(const u32x4*)&abytes[16 + ln15][kb];
      a2.u = *(const u32x4*)&abytes[32 + ln15][kb];
      a3.u = *(const u32x4*)&abytes[48 + ln15][kb];
#pragma unroll
      for (int j = 0; j < 4; ++j) {
        dosub2(a0.w[j], bhA[j].s, blA[j].s, accX0);
        dosub2(a1.w[j], bhA[j].s, blA[j].s, accX1);
        dosub2(a2.w[j], bhA[j].s, blA[j].s, accX2);
        dosub2(a3.w[j], bhA[j].s, blA[j].s, accX3);
      }
      a0.u = *(const u32x4*)&abytes[ 0 + ln15][kb + 4];
      a1.u = *(const u32x4*)&abytes[16 + ln15][kb + 4];
      a2.u = *(const u32x4*)&abytes[32 + ln15][kb + 4];
      a3.u = *(const u32x4*)&abytes[48 + ln15][kb + 4];
#pragma unroll
      for (int j = 0; j < 4; ++j) {
        dosub2(a0.w[j], bhB[j].s, blB[j].s, accX0);
        dosub2(a1.w[j], bhB[j].s, blB[j].s, accX1);
        dosub2(a2.w[j], bhB[j].s, blB[j].s, accX2);
        dosub2(a3.w[j], bhB[j].s, blB[j].s, accX3);
      }
    }
#pragma unroll
    for (int r = 0; r < 4; ++r) {
      red[wv][ 0 + g4 * 4 + r][ln15] = accX0[r];
      red[wv][16 + g4 * 4 + r][ln15] = accX1[r];
      red[wv][32 + g4 * 4 + r][ln15] = accX2[r];
      red[wv][48 + g4 * 4 + r][ln15] = accX3[r];
    }
    __syncthreads();

    // ---- ALIF state update ----
    if (upd) {
      unsigned nib = 0u;
#pragma unroll
      for (int jj = 0; jj < 4; ++jj) {
        const unsigned n = q * 4u + (unsigned)jj;
        const float dv = ((red[0][blq][n] + red[1][blq][n]) + (red[2][blq][n] + red[3][blq][n]))
                       + ((red[4][blq][n] + red[5][blq][n]) + (red[6][blq][n] + red[7][blq][n]));
        const float vv = __fsub_rn(__fadd_rn(__fmul_rn(0.8f, v[jj]), dv),
                                   __fmul_rn(zf[jj], 0.6f));
        a[jj] = __fadd_rn(__fmul_rn(0.97f, a[jj]), zf[jj]);
        const float th = __fadd_rn(0.6f, __fmul_rn(0.07f, a[jj]));
        const bool znew = vv > th;
        zf[jj] = znew ? 1.0f : 0.0f;
        v[jj] = vv;
        nib |= (znew ? 1u : 0u) << jj;
      }
      zn[blq][q] = (unsigned char)nib;
    }
    __syncthreads();

    // ---- publish z_{t+1} ----
    if (tid < 64u) {
      const unsigned m16 = (unsigned)zn[tid][0] | ((unsigned)zn[tid][1] << 4) |
                           ((unsigned)zn[tid][2] << 8) | ((unsigned)zn[tid][3] << 12);
      const unsigned nb = ((unsigned)t & 1u) ^ 1u;
      __hip_atomic_store(zb + ((nb * 2u + mh) * 64u + tid) * 128u + ns, m16,
                         AT_RLX, SC_AGT);
    }
    bar_arrive(bar);

    // ---- barrier shadow: xs_{t+1} stage, readout(z_t), accX(t+1), weight prefetch ----
    if (t < TSTEPS - 1) stage_xs(t + 1);
    if (dual && t > 0) readout_pass();
    __syncthreads();
    if (t < TSTEPS - 1) {
      compute_accX();
      prefetchA();
    }
  }

  // ---- post-loop: readout of z_199 + publish results ----
  bar_wait(bar, (unsigned)TSTEPS);
  if (dual) {
    stage_z((unsigned)TSTEPS & 1u);
    __syncthreads();
    readout_pass();
    if (ns < 2u && upd) {
#pragma unroll
      for (int jj = 0; jj < 4; ++jj) {
        __hip_atomic_store(fin + ((size_t)mh * 64u + blq) * 32u + ns * 16u + q * 4u + (unsigned)jj,
                           __float_as_uint(voMax[jj]), AT_RLX, SC_AGT);
      }
    }
    if (ns == 2u && tid < 64u) {
      out[4096u + mh * 64u + tid] = liMax;
    }
  }
  bar_arrive(bar);

  // ---- wg0: softmax over voMax ----
  if (wg == 0u) {
    bar_wait(bar, (unsigned)TSTEPS + 1u);
    if (tid < 128u) {
      float vals[32];
#pragma unroll
      for (int o = 0; o < 32; ++o)
        vals[o] = __uint_as_float(__hip_atomic_load(fin + (size_t)tid * 32u + o,
                                                    AT_RLX, SC_AGT));
      float mx = vals[0];
#pragma unroll
      for (int o = 1; o < 32; ++o) mx = fmaxf(mx, vals[o]);
      float ssum = 0.f;
#pragma unroll
      for (int o = 0; o < 32; ++o) ssum += expf(vals[o] - mx);
      const float inv = 1.0f / ssum;
#pragma unroll
      for (int o = 0; o < 32; ++o) out[(size_t)tid * 32u + o] = expf(vals[o] - mx) * inv;
    }
  }
}

// ---------------- launch ----------------
extern "C" void kernel_launch(void* const* d_in, const int* in_sizes, int n_in,
                              void* d_out, int out_size, void* d_ws, size_t ws_size,
                              hipStream_t stream)
{
  (void)in_sizes; (void)n_in; (void)out_size;
  if (ws_size < (size_t)WS_NEED) return;

  const float* x     = (const float*)d_in[0];
  const float* w_in  = (const float*)d_in[1];
  const float* w_rec = (const float*)d_in[2];
  const float* w_out = (const float*)d_in[3];
  const float* w_li  = (const float*)d_in[4];
  unsigned char* ws  = (unsigned char*)d_ws;

  unsigned*      bar  = (unsigned*)(ws + WS_BAR);
  unsigned*      zb   = (unsigned*)(ws + WS_ZB);
  unsigned*      fin  = (unsigned*)(ws + WS_FIN);
  unsigned char* xsb  = ws + WS_XSB;
  u32x4*         wf   = (u32x4*)(ws + WS_WF);

  hipMemsetAsync(bar, 0, 4096, stream);
  hipMemsetAsync(zb, 0, 131072, stream);
  k_encode<<<dim3(128), dim3(1024), 0, stream>>>(x, xsb);
  k_prep<<<dim3(3120), dim3(256), 0, stream>>>(w_rec, w_in, w_out, w_li, wf);
  k_main<<<dim3(256), dim3(512), 0, stream>>>(wf, xsb, zb, bar, fin, (float*)d_out);
}